// Round 3
// baseline (263.041 us; speedup 1.0000x reference)
//
#include <hip/hip_runtime.h>
#include <math.h>

#define NPIX 4096     // 64*64
#define NLOW 65536    // 256*256

__device__ __forceinline__ float sigmoidf_(float x){ return 1.0f/(1.0f + __expf(-x)); }

__device__ __forceinline__ float wave_sum(float v){
  #pragma unroll
  for(int o=32;o;o>>=1) v += __shfl_down(v, o, 64);
  return v;
}

// ---------------- Kernel 1: channel sum (pool) + bilinear downsample 256->64 + sumsq, one x_low pass ----
__global__ __launch_bounds__(256) void k_down(const float* __restrict__ xlow,
    float* __restrict__ xl, float* __restrict__ ssql, float* __restrict__ sum_low){
  __shared__ float sd[8];
  int bc = blockIdx.x;
  // phase A: stream whole channel, coalesced float4, for the channel mean (also warms L2)
  const float4* P = (const float4*)(xlow + (size_t)bc*NLOW);
  float s = 0.f;
  for(int i=threadIdx.x; i<NLOW/4; i+=256){
    float4 v = P[i];
    s += (v.x+v.y)+(v.z+v.w);
  }
  // phase B: bilinear gather (hits L2: the 256KB channel was just streamed)
  const float* X = xlow + (size_t)bc*NLOW;
  const float D = 255.0f/63.0f;
  float ss = 0.f;
  for(int t=threadIdx.x; t<NPIX; t+=256){
    int i = t>>6, j = t&63;
    float ph = i*D; int h0 = (int)ph; if(h0>255) h0=255; float fh = ph - (float)h0; int h1 = h0+1; if(h1>255) h1=255;
    float pw = j*D; int w0 = (int)pw; if(w0>255) w0=255; float fw = pw - (float)w0; int w1 = w0+1; if(w1>255) w1=255;
    const float* r0 = X + h0*256; const float* r1 = X + h1*256;
    float v = (1.f-fh)*((1.f-fw)*r0[w0] + fw*r0[w1]) + fh*((1.f-fw)*r1[w0] + fw*r1[w1]);
    xl[(size_t)bc*NPIX + t] = v;
    ss += v*v;
  }
  float wa = wave_sum(s), wb = wave_sum(ss);
  int w = threadIdx.x >> 6;
  if((threadIdx.x & 63) == 0){ sd[w] = wa; sd[4+w] = wb; }
  __syncthreads();
  if(threadIdx.x == 0){
    sum_low[bc] = sd[0]+sd[1]+sd[2]+sd[3];
    ssql[bc]    = sd[4]+sd[5]+sd[6]+sd[7];
  }
}

// ---------------- Kernel 2: per-(b,d) sumsq of x_high ----------------
__global__ __launch_bounds__(256) void k_ssqh(const float* __restrict__ xh, float* __restrict__ ssqh){
  __shared__ float sd[4];
  int bd = blockIdx.x;
  const float4* P = (const float4*)(xh + (size_t)bd*NPIX);
  float s = 0.f;
  for(int i=threadIdx.x; i<NPIX/4; i+=256){
    float4 v = P[i];
    s += v.x*v.x + v.y*v.y + v.z*v.z + v.w*v.w;
  }
  float w = wave_sum(s);
  if((threadIdx.x & 63) == 0) sd[threadIdx.x >> 6] = w;
  __syncthreads();
  if(threadIdx.x == 0) ssqh[bd] = sd[0]+sd[1]+sd[2]+sd[3];
}

// ---------------- Kernel 3: cos partial dots over n-chunks of 64 ----------------
__global__ __launch_bounds__(256) void k_cospart(const float* __restrict__ xl,
                                                 const float* __restrict__ xh,
                                                 float* __restrict__ cospart){
  __shared__ float xls[64*65];
  __shared__ float xhs[128*65];
  int b = blockIdx.x >> 6;
  int chk = blockIdx.x & 63;
  int n0 = chk * 64;
  for(int idx = threadIdx.x; idx < 64*64; idx += 256){
    int c = idx >> 6, k = idx & 63;
    xls[c*65 + k] = xl[((size_t)b*64 + c)*NPIX + n0 + k];
  }
  for(int idx = threadIdx.x; idx < 128*64; idx += 256){
    int d = idx >> 6, k = idx & 63;
    xhs[d*65 + k] = xh[((size_t)b*128 + d)*NPIX + n0 + k];
  }
  __syncthreads();
  int ci = threadIdx.x & 15, di = threadIdx.x >> 4;
  int c0 = ci*4, d0 = di*8;
  float acc[4][8];
  #pragma unroll
  for(int i=0;i<4;i++)
    #pragma unroll
    for(int j=0;j<8;j++) acc[i][j] = 0.f;
  for(int k=0;k<64;k++){
    float a0 = xls[(c0+0)*65 + k];
    float a1 = xls[(c0+1)*65 + k];
    float a2 = xls[(c0+2)*65 + k];
    float a3 = xls[(c0+3)*65 + k];
    #pragma unroll
    for(int j=0;j<8;j++){
      float bv = xhs[(d0+j)*65 + k];
      acc[0][j] += a0*bv; acc[1][j] += a1*bv; acc[2][j] += a2*bv; acc[3][j] += a3*bv;
    }
  }
  float* op = cospart + (size_t)(b*64 + chk)*8192;
  #pragma unroll
  for(int i=0;i<4;i++){
    float4 v0 = make_float4(acc[i][0],acc[i][1],acc[i][2],acc[i][3]);
    float4 v1 = make_float4(acc[i][4],acc[i][5],acc[i][6],acc[i][7]);
    float4* dst = (float4*)(op + (c0+i)*128 + d0);
    dst[0] = v0; dst[1] = v1;
  }
}

// ---------------- Kernel 4: reduce partials, normalize, softmax over d -> p[b][c][d] ----------------
__global__ __launch_bounds__(128) void k_softmax(const float* __restrict__ cospart,
    const float* __restrict__ ssql, const float* __restrict__ ssqh, float* __restrict__ p){
  int b = blockIdx.x >> 6, c = blockIdx.x & 63;
  int d = threadIdx.x;
  float s = 0.f;
  for(int chk=0; chk<64; chk++)
    s += cospart[(size_t)(b*64 + chk)*8192 + c*128 + d];
  float nl = sqrtf(ssql[b*64 + c]) + 1e-12f;
  float nh = sqrtf(ssqh[b*128 + d]) + 1e-12f;
  float cosv = s / (nl * nh);
  __shared__ float sm[2], ssum[2];
  float m = cosv;
  #pragma unroll
  for(int o=32;o;o>>=1) m = fmaxf(m, __shfl_xor(m, o, 64));
  if((threadIdx.x & 63) == 0) sm[threadIdx.x >> 6] = m;
  __syncthreads();
  m = fmaxf(sm[0], sm[1]);
  float e = __expf(cosv - m);
  float t = e;
  #pragma unroll
  for(int o=32;o;o>>=1) t += __shfl_xor(t, o, 64);
  if((threadIdx.x & 63) == 0) ssum[threadIdx.x >> 6] = t;
  __syncthreads();
  t = ssum[0] + ssum[1];
  p[(size_t)(b*64 + c)*128 + d] = e / t;
}

// ---------------- Kernel 5: fused xhc = P @ xh and red64 = relu(bn(red_w @ xh)) ----------------
// grid = B * 64 n-chunks of 64; P staged [128][65] in two K-halves (stays < 64KB, conflict-free reads)
__global__ __launch_bounds__(256) void k_pv(const float* __restrict__ p, const float* __restrict__ red_w,
    const float* __restrict__ xh,
    const float* __restrict__ rg, const float* __restrict__ rb,
    const float* __restrict__ rm, const float* __restrict__ rv,
    float* __restrict__ xhc, float* __restrict__ red64){
  __shared__ float P_s[128*65];   // 33 KB
  int b = blockIdx.x >> 6, chk = blockIdx.x & 63;
  int n0 = chk * 64;
  int ni = threadIdx.x & 7, ri = threadIdx.x >> 3;   // ni: 8 n-groups of 8; ri: 32 r-groups of 4
  int r0 = 4*ri;
  float acc[4][8];
  #pragma unroll
  for(int i=0;i<4;i++)
    #pragma unroll
    for(int j=0;j<8;j++) acc[i][j] = 0.f;
  const float* xrow = xh + (size_t)b*128*NPIX + n0 + 8*ni;
  for(int half=0; half<2; ++half){
    int kb = half*64;
    __syncthreads();
    for(int idx = threadIdx.x; idx < 128*64; idx += 256){
      int r = idx >> 6, kk = idx & 63;
      int k = kb + kk;
      P_s[r*65 + kk] = (r < 64) ? p[((size_t)b*64 + r)*128 + k]
                                : red_w[(size_t)(r-64)*128 + k];
    }
    __syncthreads();
    #pragma unroll 4
    for(int kk=0; kk<64; ++kk){
      int k = kb + kk;
      float4 x0 = *(const float4*)(xrow + (size_t)k*NPIX);
      float4 x1 = *(const float4*)(xrow + (size_t)k*NPIX + 4);
      #pragma unroll
      for(int rr=0; rr<4; rr++){
        float pw = P_s[(r0+rr)*65 + kk];
        acc[rr][0] += pw*x0.x; acc[rr][1] += pw*x0.y; acc[rr][2] += pw*x0.z; acc[rr][3] += pw*x0.w;
        acc[rr][4] += pw*x1.x; acc[rr][5] += pw*x1.y; acc[rr][6] += pw*x1.z; acc[rr][7] += pw*x1.w;
      }
    }
  }
  #pragma unroll
  for(int rr=0; rr<4; rr++){
    int r = r0 + rr;
    if(r < 64){
      float* dst = xhc + ((size_t)b*64 + r)*NPIX + n0 + 8*ni;
      *(float4*)dst     = make_float4(acc[rr][0],acc[rr][1],acc[rr][2],acc[rr][3]);
      *(float4*)(dst+4) = make_float4(acc[rr][4],acc[rr][5],acc[rr][6],acc[rr][7]);
    } else {
      int o = r - 64;
      float sc = rg[o] * rsqrtf(rv[o] + 1e-5f);
      float bs = rb[o] - rm[o]*sc;
      float* dst = red64 + ((size_t)b*64 + o)*NPIX + n0 + 8*ni;
      *(float4*)dst     = make_float4(fmaxf(fmaf(acc[rr][0],sc,bs),0.f), fmaxf(fmaf(acc[rr][1],sc,bs),0.f),
                                      fmaxf(fmaf(acc[rr][2],sc,bs),0.f), fmaxf(fmaf(acc[rr][3],sc,bs),0.f));
      *(float4*)(dst+4) = make_float4(fmaxf(fmaf(acc[rr][4],sc,bs),0.f), fmaxf(fmaf(acc[rr][5],sc,bs),0.f),
                                      fmaxf(fmaf(acc[rr][6],sc,bs),0.f), fmaxf(fmaf(acc[rr][7],sc,bs),0.f));
    }
  }
}

// ---------------- Kernel 6: weighted mean of upsampled red via Wv (Wv folded in) ----------------
__global__ __launch_bounds__(256) void k_redmean(const float* __restrict__ red64, float* __restrict__ redmean){
  __shared__ float wv[64];
  __shared__ float sd[4];
  int bo = blockIdx.x;
  if(threadIdx.x < 64){
    int i = threadIdx.x;
    const float U = 63.0f/255.0f;
    float acc = 0.f;
    for(int k=0;k<256;k++){
      float pos = k*U;
      int i0 = (int)pos; if(i0>63) i0=63;
      float f = pos - (float)i0;
      int i1 = i0+1; if(i1>63) i1=63;
      if(i0==i) acc += 1.0f - f;
      if(i1==i) acc += f;
    }
    wv[i] = acc;
  }
  __syncthreads();
  const float* R = red64 + (size_t)bo*NPIX;
  float acc = 0.f;
  for(int t=threadIdx.x; t<NPIX; t+=256){
    int i = t>>6, j = t&63;
    acc += wv[i]*wv[j]*R[t];
  }
  float w = wave_sum(acc);
  if((threadIdx.x & 63) == 0) sd[threadIdx.x >> 6] = w;
  __syncthreads();
  if(threadIdx.x == 0) redmean[bo] = (sd[0]+sd[1]+sd[2]+sd[3]) * (1.0f/65536.0f);
}

// ---------------- Kernel 7: final fused: att gate + 2x upsample + sigmoid diffs + relu ----------------
// one block per (b,c); 4x4 output tile per thread: 3x3 LDS neighborhood serves 16 pixels.
__global__ __launch_bounds__(256) void k_final(const float* __restrict__ xlow,
    const float* __restrict__ xhc, const float* __restrict__ red64,
    const float* __restrict__ sum_low, const float* __restrict__ redmean,
    const float* __restrict__ cw, const float* __restrict__ cb,
    const float* __restrict__ g, const float* __restrict__ be,
    const float* __restrict__ mu, const float* __restrict__ va,
    float* __restrict__ out){
  __shared__ float sx[NPIX];
  __shared__ float sr[NPIX];
  __shared__ float s_red[2];
  __shared__ float s_att;
  int b = blockIdx.x >> 6, c = blockIdx.x & 63;
  // stage the two 64x64 maps
  {
    const float4* A  = (const float4*)(xhc   + ((size_t)b*64 + c)*NPIX);
    const float4* Rr = (const float4*)(red64 + ((size_t)b*64 + c)*NPIX);
    for(int i=threadIdx.x; i<NPIX/4; i+=256){
      ((float4*)sx)[i] = A[i];
      ((float4*)sr)[i] = Rr[i];
    }
  }
  // channel-gate att for this (b,c): dot(cconv_w[c], pool[b]) on threads 0..127
  if(threadIdx.x < 128){
    int j = threadIdx.x;
    float pj = (j < 64) ? sum_low[b*64 + j]*(1.0f/65536.0f) : redmean[b*64 + (j-64)];
    float t = cw[c*128 + j] * pj;
    float w = wave_sum(t);
    if((j & 63) == 0) s_red[j >> 6] = w;
  }
  __syncthreads();
  if(threadIdx.x == 0){
    float acc = s_red[0] + s_red[1] + cb[c];
    float sc = g[c] * rsqrtf(va[c] + 1e-5f);
    s_att = sigmoidf_((acc - mu[c])*sc + be[c]);
  }
  __syncthreads();
  float a = s_att;

  const float U = 63.0f/255.0f;
  int ct = threadIdx.x & 63;   // column tile: output cols 4ct..4ct+3
  int rt = threadIdx.x >> 6;   // row group 0..3
  // per-thread column weights (constant over all rows)
  int w0_[4]; float fw_[4];
  #pragma unroll
  for(int i=0;i<4;i++){
    int w = 4*ct + i;
    float pw = w*U;
    int w0 = (int)pw; if(w0 > 63) w0 = 63;
    w0_[i] = w0; fw_[i] = pw - (float)w0;
  }
  int c0 = w0_[0];
  const float* XL = xlow + ((size_t)b*64 + c)*NLOW;
  float* O1 = out + ((size_t)(b*128) + c)*NLOW;
  float* O2 = O1 + (size_t)64*NLOW;

  for(int it=0; it<16; ++it){
    int hbase = it*16 + rt*4;      // output rows hbase..hbase+3
    int r0 = (int)(hbase*U); if(r0 > 63) r0 = 63;
    // 3x3 clamped neighborhood from LDS (covers the <=2x2 input span of the 4x4 tile)
    float ax[3][3], ar[3][3];
    #pragma unroll
    for(int rr=0; rr<3; rr++){
      int rcl = r0 + rr; if(rcl > 63) rcl = 63;
      int rb_ = rcl*64;
      #pragma unroll
      for(int cc=0; cc<3; cc++){
        int ccl = c0 + cc; if(ccl > 63) ccl = 63;
        ax[rr][cc] = sx[rb_ + ccl];
        ar[rr][cc] = sr[rb_ + ccl];
      }
    }
    // horizontal interp: 3 input rows x 4 output cols
    float tx[3][4], tr_[3][4];
    #pragma unroll
    for(int rr=0; rr<3; rr++){
      #pragma unroll
      for(int i=0;i<4;i++){
        int dw = w0_[i] - c0;
        tx[rr][i]  = ax[rr][dw] + fw_[i]*(ax[rr][dw+1] - ax[rr][dw]);
        tr_[rr][i] = ar[rr][dw] + fw_[i]*(ar[rr][dw+1] - ar[rr][dw]);
      }
    }
    // vertical interp + sigmoid diffs, 4 output rows
    #pragma unroll
    for(int hh=0; hh<4; ++hh){
      int h = hbase + hh;
      float ph = h*U;
      int h0 = (int)ph; if(h0 > 63) h0 = 63;
      float fh = ph - (float)h0;
      int dr = h0 - r0;            // 0 or 1
      float4 xv = *(const float4*)(XL + h*256 + ct*4);
      float xvv[4] = {xv.x, xv.y, xv.z, xv.w};
      float o1[4], o2[4];
      #pragma unroll
      for(int i=0;i<4;i++){
        float vx = tx[dr][i]  + fh*(tx[dr+1][i]  - tx[dr][i]);
        float vr = tr_[dr][i] + fh*(tr_[dr+1][i] - tr_[dr][i]);
        float sl = sigmoidf_(xvv[i]);
        o1[i] = fmaxf(sl - sigmoidf_(vx), 0.f);
        o2[i] = fmaxf(sl - sigmoidf_(vr*a), 0.f);
      }
      *(float4*)(O1 + h*256 + ct*4) = make_float4(o1[0],o1[1],o1[2],o1[3]);
      *(float4*)(O2 + h*256 + ct*4) = make_float4(o2[0],o2[1],o2[2],o2[3]);
    }
  }
}

extern "C" void kernel_launch(void* const* d_in, const int* in_sizes, int n_in,
                              void* d_out, int out_size, void* d_ws, size_t ws_size,
                              hipStream_t stream) {
  const float* x_low   = (const float*)d_in[0];
  const float* x_high  = (const float*)d_in[1];
  const float* red_w   = (const float*)d_in[2];
  const float* red_g   = (const float*)d_in[3];
  const float* red_b   = (const float*)d_in[4];
  const float* red_m   = (const float*)d_in[5];
  const float* red_v   = (const float*)d_in[6];
  const float* cconv_w = (const float*)d_in[7];
  const float* cconv_b = (const float*)d_in[8];
  const float* cc_g    = (const float*)d_in[9];
  const float* cc_b    = (const float*)d_in[10];
  const float* cc_m    = (const float*)d_in[11];
  const float* cc_v    = (const float*)d_in[12];
  float* out = (float*)d_out;
  float* ws  = (float*)d_ws;

  float* bufA    = ws;               // xl (2,097,152 floats), later red64
  float* bufB    = ws + 2097152;     // cospart (4,194,304), later xhc (2,097,152)
  float* p       = ws + 6291456;     // 65,536
  float* sum_low = ws + 6356992;     // 512
  float* ssql    = ws + 6357504;     // 512
  float* ssqh    = ws + 6358016;     // 1024
  float* redmean = ws + 6359040;     // 512

  hipLaunchKernelGGL(k_down,    dim3(512),  dim3(256), 0, stream, x_low, bufA, ssql, sum_low);
  hipLaunchKernelGGL(k_ssqh,    dim3(1024), dim3(256), 0, stream, x_high, ssqh);
  hipLaunchKernelGGL(k_cospart, dim3(512),  dim3(256), 0, stream, bufA, x_high, bufB);
  hipLaunchKernelGGL(k_softmax, dim3(512),  dim3(128), 0, stream, bufB, ssql, ssqh, p);
  hipLaunchKernelGGL(k_pv,      dim3(512),  dim3(256), 0, stream, p, red_w, x_high,
                     red_g, red_b, red_m, red_v, bufB, bufA);
  hipLaunchKernelGGL(k_redmean, dim3(512),  dim3(256), 0, stream, bufA, redmean);
  hipLaunchKernelGGL(k_final,   dim3(512),  dim3(256), 0, stream, x_low, bufB, bufA,
                     sum_low, redmean, cconv_w, cconv_b, cc_g, cc_b, cc_m, cc_v, out);
}

// Round 4
// 231.188 us; speedup vs baseline: 1.1378x; 1.1378x over previous
//
#include <hip/hip_runtime.h>
#include <math.h>

#define NPIX 4096     // 64*64
#define NLOW 65536    // 256*256
#define NRSTAGE 19    // max input rows needed by 64 output rows (64*63/255 span + borders)

__device__ __forceinline__ float sigmoidf_(float x){
  // v_exp + v_rcp (quarter-rate each) instead of IEEE divide expansion
  return __builtin_amdgcn_rcpf(1.0f + __expf(-x));
}

__device__ __forceinline__ float wave_sum(float v){
  #pragma unroll
  for(int o=32;o;o>>=1) v += __shfl_down(v, o, 64);
  return v;
}

// ---------------- Kernel 1: channel sum (pool) + bilinear downsample 256->64 + sumsq, one x_low pass ----
__global__ __launch_bounds__(512) void k_down(const float* __restrict__ xlow,
    float* __restrict__ xl, float* __restrict__ ssql, float* __restrict__ sum_low){
  __shared__ float sd[16];
  int bc = blockIdx.x;
  // phase A: stream whole channel, coalesced float4, for the channel mean (also warms L2/L3)
  const float4* P = (const float4*)(xlow + (size_t)bc*NLOW);
  float s = 0.f;
  for(int i=threadIdx.x; i<NLOW/4; i+=512){
    float4 v = P[i];
    s += (v.x+v.y)+(v.z+v.w);
  }
  // phase B: bilinear gather (hits L2: the 256KB channel was just streamed)
  const float* X = xlow + (size_t)bc*NLOW;
  const float D = 255.0f/63.0f;
  float ss = 0.f;
  for(int t=threadIdx.x; t<NPIX; t+=512){
    int i = t>>6, j = t&63;
    float ph = i*D; int h0 = (int)ph; if(h0>255) h0=255; float fh = ph - (float)h0; int h1 = h0+1; if(h1>255) h1=255;
    float pw = j*D; int w0 = (int)pw; if(w0>255) w0=255; float fw = pw - (float)w0; int w1 = w0+1; if(w1>255) w1=255;
    const float* r0 = X + h0*256; const float* r1 = X + h1*256;
    float v = (1.f-fh)*((1.f-fw)*r0[w0] + fw*r0[w1]) + fh*((1.f-fw)*r1[w0] + fw*r1[w1]);
    xl[(size_t)bc*NPIX + t] = v;
    ss += v*v;
  }
  float wa = wave_sum(s), wb = wave_sum(ss);
  int w = threadIdx.x >> 6;
  if((threadIdx.x & 63) == 0){ sd[w] = wa; sd[8+w] = wb; }
  __syncthreads();
  if(threadIdx.x == 0){
    float a = 0.f, b2 = 0.f;
    #pragma unroll
    for(int i=0;i<8;i++){ a += sd[i]; b2 += sd[8+i]; }
    sum_low[bc] = a;
    ssql[bc]    = b2;
  }
}

// ---------------- Kernel 2: per-(b,d) sumsq of x_high ----------------
__global__ __launch_bounds__(256) void k_ssqh(const float* __restrict__ xh, float* __restrict__ ssqh){
  __shared__ float sd[4];
  int bd = blockIdx.x;
  const float4* P = (const float4*)(xh + (size_t)bd*NPIX);
  float s = 0.f;
  for(int i=threadIdx.x; i<NPIX/4; i+=256){
    float4 v = P[i];
    s += v.x*v.x + v.y*v.y + v.z*v.z + v.w*v.w;
  }
  float w = wave_sum(s);
  if((threadIdx.x & 63) == 0) sd[threadIdx.x >> 6] = w;
  __syncthreads();
  if(threadIdx.x == 0) ssqh[bd] = sd[0]+sd[1]+sd[2]+sd[3];
}

// ---------------- Kernel 3: cos partial dots over n-chunks of 64 ----------------
__global__ __launch_bounds__(256) void k_cospart(const float* __restrict__ xl,
                                                 const float* __restrict__ xh,
                                                 float* __restrict__ cospart){
  __shared__ float xls[64*65];
  __shared__ float xhs[128*65];
  int b = blockIdx.x >> 6;
  int chk = blockIdx.x & 63;
  int n0 = chk * 64;
  for(int idx = threadIdx.x; idx < 64*64; idx += 256){
    int c = idx >> 6, k = idx & 63;
    xls[c*65 + k] = xl[((size_t)b*64 + c)*NPIX + n0 + k];
  }
  for(int idx = threadIdx.x; idx < 128*64; idx += 256){
    int d = idx >> 6, k = idx & 63;
    xhs[d*65 + k] = xh[((size_t)b*128 + d)*NPIX + n0 + k];
  }
  __syncthreads();
  int ci = threadIdx.x & 15, di = threadIdx.x >> 4;
  int c0 = ci*4, d0 = di*8;
  float acc[4][8];
  #pragma unroll
  for(int i=0;i<4;i++)
    #pragma unroll
    for(int j=0;j<8;j++) acc[i][j] = 0.f;
  for(int k=0;k<64;k++){
    float a0 = xls[(c0+0)*65 + k];
    float a1 = xls[(c0+1)*65 + k];
    float a2 = xls[(c0+2)*65 + k];
    float a3 = xls[(c0+3)*65 + k];
    #pragma unroll
    for(int j=0;j<8;j++){
      float bv = xhs[(d0+j)*65 + k];
      acc[0][j] += a0*bv; acc[1][j] += a1*bv; acc[2][j] += a2*bv; acc[3][j] += a3*bv;
    }
  }
  float* op = cospart + (size_t)(b*64 + chk)*8192;
  #pragma unroll
  for(int i=0;i<4;i++){
    float4 v0 = make_float4(acc[i][0],acc[i][1],acc[i][2],acc[i][3]);
    float4 v1 = make_float4(acc[i][4],acc[i][5],acc[i][6],acc[i][7]);
    float4* dst = (float4*)(op + (c0+i)*128 + d0);
    dst[0] = v0; dst[1] = v1;
  }
}

// ---------------- Kernel 4: reduce partials, normalize, softmax over d -> p[b][c][d] ----------------
__global__ __launch_bounds__(128) void k_softmax(const float* __restrict__ cospart,
    const float* __restrict__ ssql, const float* __restrict__ ssqh, float* __restrict__ p){
  int b = blockIdx.x >> 6, c = blockIdx.x & 63;
  int d = threadIdx.x;
  float s = 0.f;
  for(int chk=0; chk<64; chk++)
    s += cospart[(size_t)(b*64 + chk)*8192 + c*128 + d];
  float nl = sqrtf(ssql[b*64 + c]) + 1e-12f;
  float nh = sqrtf(ssqh[b*128 + d]) + 1e-12f;
  float cosv = s / (nl * nh);
  __shared__ float sm[2], ssum[2];
  float m = cosv;
  #pragma unroll
  for(int o=32;o;o>>=1) m = fmaxf(m, __shfl_xor(m, o, 64));
  if((threadIdx.x & 63) == 0) sm[threadIdx.x >> 6] = m;
  __syncthreads();
  m = fmaxf(sm[0], sm[1]);
  float e = __expf(cosv - m);
  float t = e;
  #pragma unroll
  for(int o=32;o;o>>=1) t += __shfl_xor(t, o, 64);
  if((threadIdx.x & 63) == 0) ssum[threadIdx.x >> 6] = t;
  __syncthreads();
  t = ssum[0] + ssum[1];
  p[(size_t)(b*64 + c)*128 + d] = e * __builtin_amdgcn_rcpf(t);
}

// ---------------- Kernel 5: fused xhc = P @ xh and red64 = relu(bn(red_w @ xh)) ----------------
__global__ __launch_bounds__(256) void k_pv(const float* __restrict__ p, const float* __restrict__ red_w,
    const float* __restrict__ xh,
    const float* __restrict__ rg, const float* __restrict__ rb,
    const float* __restrict__ rm, const float* __restrict__ rv,
    float* __restrict__ xhc, float* __restrict__ red64){
  __shared__ float P_s[128*65];   // 33 KB
  int b = blockIdx.x >> 6, chk = blockIdx.x & 63;
  int n0 = chk * 64;
  int ni = threadIdx.x & 7, ri = threadIdx.x >> 3;
  int r0 = 4*ri;
  float acc[4][8];
  #pragma unroll
  for(int i=0;i<4;i++)
    #pragma unroll
    for(int j=0;j<8;j++) acc[i][j] = 0.f;
  const float* xrow = xh + (size_t)b*128*NPIX + n0 + 8*ni;
  for(int half=0; half<2; ++half){
    int kb = half*64;
    __syncthreads();
    for(int idx = threadIdx.x; idx < 128*64; idx += 256){
      int r = idx >> 6, kk = idx & 63;
      int k = kb + kk;
      P_s[r*65 + kk] = (r < 64) ? p[((size_t)b*64 + r)*128 + k]
                                : red_w[(size_t)(r-64)*128 + k];
    }
    __syncthreads();
    #pragma unroll 4
    for(int kk=0; kk<64; ++kk){
      int k = kb + kk;
      float4 x0 = *(const float4*)(xrow + (size_t)k*NPIX);
      float4 x1 = *(const float4*)(xrow + (size_t)k*NPIX + 4);
      #pragma unroll
      for(int rr=0; rr<4; rr++){
        float pw = P_s[(r0+rr)*65 + kk];
        acc[rr][0] += pw*x0.x; acc[rr][1] += pw*x0.y; acc[rr][2] += pw*x0.z; acc[rr][3] += pw*x0.w;
        acc[rr][4] += pw*x1.x; acc[rr][5] += pw*x1.y; acc[rr][6] += pw*x1.z; acc[rr][7] += pw*x1.w;
      }
    }
  }
  #pragma unroll
  for(int rr=0; rr<4; rr++){
    int r = r0 + rr;
    if(r < 64){
      float* dst = xhc + ((size_t)b*64 + r)*NPIX + n0 + 8*ni;
      *(float4*)dst     = make_float4(acc[rr][0],acc[rr][1],acc[rr][2],acc[rr][3]);
      *(float4*)(dst+4) = make_float4(acc[rr][4],acc[rr][5],acc[rr][6],acc[rr][7]);
    } else {
      int o = r - 64;
      float sc = rg[o] * rsqrtf(rv[o] + 1e-5f);
      float bs = rb[o] - rm[o]*sc;
      float* dst = red64 + ((size_t)b*64 + o)*NPIX + n0 + 8*ni;
      *(float4*)dst     = make_float4(fmaxf(fmaf(acc[rr][0],sc,bs),0.f), fmaxf(fmaf(acc[rr][1],sc,bs),0.f),
                                      fmaxf(fmaf(acc[rr][2],sc,bs),0.f), fmaxf(fmaf(acc[rr][3],sc,bs),0.f));
      *(float4*)(dst+4) = make_float4(fmaxf(fmaf(acc[rr][4],sc,bs),0.f), fmaxf(fmaf(acc[rr][5],sc,bs),0.f),
                                      fmaxf(fmaf(acc[rr][6],sc,bs),0.f), fmaxf(fmaf(acc[rr][7],sc,bs),0.f));
    }
  }
}

// ---------------- Kernel 6: weighted mean of upsampled red via Wv (Wv folded in) ----------------
__global__ __launch_bounds__(256) void k_redmean(const float* __restrict__ red64, float* __restrict__ redmean){
  __shared__ float wv[64];
  __shared__ float sd[4];
  int bo = blockIdx.x;
  if(threadIdx.x < 64){
    int i = threadIdx.x;
    const float U = 63.0f/255.0f;
    float acc = 0.f;
    for(int k=0;k<256;k++){
      float pos = k*U;
      int i0 = (int)pos; if(i0>63) i0=63;
      float f = pos - (float)i0;
      int i1 = i0+1; if(i1>63) i1=63;
      if(i0==i) acc += 1.0f - f;
      if(i1==i) acc += f;
    }
    wv[i] = acc;
  }
  __syncthreads();
  const float* R = red64 + (size_t)bo*NPIX;
  float acc = 0.f;
  for(int t=threadIdx.x; t<NPIX; t+=256){
    int i = t>>6, j = t&63;
    acc += wv[i]*wv[j]*R[t];
  }
  float w = wave_sum(acc);
  if((threadIdx.x & 63) == 0) sd[threadIdx.x >> 6] = w;
  __syncthreads();
  if(threadIdx.x == 0) redmean[bo] = (sd[0]+sd[1]+sd[2]+sd[3]) * (1.0f/65536.0f);
}

// ---------------- Kernel 7: final fused: att gate + 2x upsample + sigmoid diffs + relu ----------------
// grid = B*64*4: one block per (b, c, 64-row output slice). Stages only the 19 input rows
// the slice needs (9.7 KB LDS) -> 8 blocks/CU = 32 waves/CU.
__global__ __launch_bounds__(256) void k_final(const float* __restrict__ xlow,
    const float* __restrict__ xhc, const float* __restrict__ red64,
    const float* __restrict__ sum_low, const float* __restrict__ redmean,
    const float* __restrict__ cw, const float* __restrict__ cb,
    const float* __restrict__ g, const float* __restrict__ be,
    const float* __restrict__ mu, const float* __restrict__ va,
    float* __restrict__ out){
  __shared__ float sx[NRSTAGE*64];
  __shared__ float sr[NRSTAGE*64];
  __shared__ float s_red[2];
  __shared__ float s_att;
  int bc = blockIdx.x >> 2;        // b*64 + c
  int sl_ = blockIdx.x & 3;        // row-quarter
  int b = bc >> 6, c = bc & 63;
  int h_start = sl_ * 64;
  const float U = 63.0f/255.0f;
  int r_lo = (int)(h_start*U);
  // stage the 19 input rows (clamped) of both 64x64 maps, float4-coalesced
  {
    const float* Ax = xhc   + (size_t)bc*NPIX;
    const float* Ar = red64 + (size_t)bc*NPIX;
    for(int i=threadIdx.x; i<NRSTAGE*16; i+=256){
      int row = i>>4, c4 = i&15;
      int srow = r_lo + row; if(srow > 63) srow = 63;
      ((float4*)sx)[i] = *(const float4*)(Ax + srow*64 + c4*4);
      ((float4*)sr)[i] = *(const float4*)(Ar + srow*64 + c4*4);
    }
  }
  // channel-gate att for this (b,c)
  if(threadIdx.x < 128){
    int j = threadIdx.x;
    float pj = (j < 64) ? sum_low[b*64 + j]*(1.0f/65536.0f) : redmean[b*64 + (j-64)];
    float t = cw[c*128 + j] * pj;
    float w = wave_sum(t);
    if((j & 63) == 0) s_red[j >> 6] = w;
  }
  __syncthreads();
  if(threadIdx.x == 0){
    float acc = s_red[0] + s_red[1] + cb[c];
    float sc = g[c] * rsqrtf(va[c] + 1e-5f);
    s_att = sigmoidf_((acc - mu[c])*sc + be[c]);
  }
  __syncthreads();
  float a = s_att;

  int ct = threadIdx.x & 63;   // column tile: output cols 4ct..4ct+3
  int rt = threadIdx.x >> 6;   // row group 0..3
  int w0_[4]; float fw_[4];
  #pragma unroll
  for(int i=0;i<4;i++){
    int w = 4*ct + i;
    float pw = w*U;
    int w0 = (int)pw; if(w0 > 63) w0 = 63;
    w0_[i] = w0; fw_[i] = pw - (float)w0;
  }
  int c0 = w0_[0];
  const float* XL = xlow + (size_t)bc*NLOW;
  float* O1 = out + ((size_t)(b*128) + c)*NLOW;
  float* O2 = O1 + (size_t)64*NLOW;

  for(int it=0; it<4; ++it){
    int hbase = h_start + it*16 + rt*4;      // output rows hbase..hbase+3
    int r0 = (int)(hbase*U);
    // 3x3 clamped neighborhood from LDS
    float ax[3][3], ar[3][3];
    #pragma unroll
    for(int rr=0; rr<3; rr++){
      int rcl = r0 + rr; if(rcl > 63) rcl = 63;
      int rb_ = (rcl - r_lo)*64;
      #pragma unroll
      for(int cc=0; cc<3; cc++){
        int ccl = c0 + cc; if(ccl > 63) ccl = 63;
        ax[rr][cc] = sx[rb_ + ccl];
        ar[rr][cc] = sr[rb_ + ccl];
      }
    }
    // horizontal interp: 3 input rows x 4 output cols
    float tx[3][4], tr_[3][4];
    #pragma unroll
    for(int rr=0; rr<3; rr++){
      #pragma unroll
      for(int i=0;i<4;i++){
        int dw = w0_[i] - c0;
        tx[rr][i]  = ax[rr][dw] + fw_[i]*(ax[rr][dw+1] - ax[rr][dw]);
        tr_[rr][i] = ar[rr][dw] + fw_[i]*(ar[rr][dw+1] - ar[rr][dw]);
      }
    }
    // vertical interp + sigmoid diffs, 4 output rows
    #pragma unroll
    for(int hh=0; hh<4; ++hh){
      int h = hbase + hh;
      float ph = h*U;
      int h0 = (int)ph; if(h0 > 63) h0 = 63;
      float fh = ph - (float)h0;
      int dr = h0 - r0;            // 0 or 1
      float4 xv = *(const float4*)(XL + h*256 + ct*4);
      float xvv[4] = {xv.x, xv.y, xv.z, xv.w};
      float o1[4], o2[4];
      #pragma unroll
      for(int i=0;i<4;i++){
        float vx = tx[dr][i]  + fh*(tx[dr+1][i]  - tx[dr][i]);
        float vr = tr_[dr][i] + fh*(tr_[dr+1][i] - tr_[dr][i]);
        float sl = sigmoidf_(xvv[i]);
        o1[i] = fmaxf(sl - sigmoidf_(vx), 0.f);
        o2[i] = fmaxf(sl - sigmoidf_(vr*a), 0.f);
      }
      *(float4*)(O1 + h*256 + ct*4) = make_float4(o1[0],o1[1],o1[2],o1[3]);
      *(float4*)(O2 + h*256 + ct*4) = make_float4(o2[0],o2[1],o2[2],o2[3]);
    }
  }
}

extern "C" void kernel_launch(void* const* d_in, const int* in_sizes, int n_in,
                              void* d_out, int out_size, void* d_ws, size_t ws_size,
                              hipStream_t stream) {
  const float* x_low   = (const float*)d_in[0];
  const float* x_high  = (const float*)d_in[1];
  const float* red_w   = (const float*)d_in[2];
  const float* red_g   = (const float*)d_in[3];
  const float* red_b   = (const float*)d_in[4];
  const float* red_m   = (const float*)d_in[5];
  const float* red_v   = (const float*)d_in[6];
  const float* cconv_w = (const float*)d_in[7];
  const float* cconv_b = (const float*)d_in[8];
  const float* cc_g    = (const float*)d_in[9];
  const float* cc_b    = (const float*)d_in[10];
  const float* cc_m    = (const float*)d_in[11];
  const float* cc_v    = (const float*)d_in[12];
  float* out = (float*)d_out;
  float* ws  = (float*)d_ws;

  float* bufA    = ws;               // xl (2,097,152 floats), later red64
  float* bufB    = ws + 2097152;     // cospart (4,194,304), later xhc (2,097,152)
  float* p       = ws + 6291456;     // 65,536
  float* sum_low = ws + 6356992;     // 512
  float* ssql    = ws + 6357504;     // 512
  float* ssqh    = ws + 6358016;     // 1024
  float* redmean = ws + 6359040;     // 512

  hipLaunchKernelGGL(k_down,    dim3(512),  dim3(512), 0, stream, x_low, bufA, ssql, sum_low);
  hipLaunchKernelGGL(k_ssqh,    dim3(1024), dim3(256), 0, stream, x_high, ssqh);
  hipLaunchKernelGGL(k_cospart, dim3(512),  dim3(256), 0, stream, bufA, x_high, bufB);
  hipLaunchKernelGGL(k_softmax, dim3(512),  dim3(128), 0, stream, bufB, ssql, ssqh, p);
  hipLaunchKernelGGL(k_pv,      dim3(512),  dim3(256), 0, stream, p, red_w, x_high,
                     red_g, red_b, red_m, red_v, bufB, bufA);
  hipLaunchKernelGGL(k_redmean, dim3(512),  dim3(256), 0, stream, bufA, redmean);
  hipLaunchKernelGGL(k_final,   dim3(2048), dim3(256), 0, stream, x_low, bufB, bufA,
                     sum_low, redmean, cconv_w, cconv_b, cc_g, cc_b, cc_m, cc_v, out);
}

// Round 5
// 187.093 us; speedup vs baseline: 1.4059x; 1.2357x over previous
//
#include <hip/hip_runtime.h>
#include <math.h>

#define NPIX 4096     // 64*64
#define NLOW 65536    // 256*256
#define NRSTAGE 19    // max input rows needed by a 64-output-row slice

__device__ __forceinline__ float sigmoidf_(float x){
  return __builtin_amdgcn_rcpf(1.0f + __expf(-x));
}

__device__ __forceinline__ float wave_sum(float v){
  #pragma unroll
  for(int o=32;o;o>>=1) v += __shfl_down(v, o, 64);
  return v;
}

// ---------------- Kernel 1: single-pass channel sum + bilinear downsample 256->64 + sumsq ----
// One block per (b,c) channel, 512 threads. Streams the channel ONCE (coalesced float4),
// staging 17 rows at a time in LDS; downsample taps read from LDS. No uncoalesced gather.
__global__ __launch_bounds__(512) void k_down(const float* __restrict__ xlow,
    float* __restrict__ xl, float* __restrict__ ssql, float* __restrict__ sum_low){
  __shared__ float rows[17*256];   // 17 KB
  __shared__ float sd[16];
  int bc = blockIdx.x;
  const float4* X4 = (const float4*)(xlow + (size_t)bc*NLOW);
  float4* R4 = (float4*)rows;
  const float D = 255.0f/63.0f;
  float sum = 0.f, ssq = 0.f;
  int rt = threadIdx.x >> 6, j = threadIdx.x & 63;

  for(int it=0; it<16; ++it){
    int base = 16*it;
    __syncthreads();   // protect previous window's reads
    // stage 16 rows (coalesced) + accumulate channel sum
    for(int i=threadIdx.x; i<1024; i+=512){
      float4 v = X4[base*64 + i];
      R4[i] = v;
      sum += (v.x+v.y)+(v.z+v.w);
    }
    // overlap row base+16 (clamped), not added to sum
    if(threadIdx.x < 64){
      int srow = base+16; if(srow > 255) srow = 255;
      R4[1024 + threadIdx.x] = X4[srow*64 + threadIdx.x];
    }
    __syncthreads();
    // output rows whose h0 falls in [base, base+16)
    int i0 = (int)ceilf((float)base / D);
    int i = i0 + rt;          // rt in 0..7, window holds <=4-5 valid rows
    if(i < 64){
      float ph = i*D; int h0 = (int)ph; if(h0 > 255) h0 = 255;
      if((h0 >> 4) == it){
        float fh = ph - (float)h0;
        int h1 = h0+1; if(h1 > 255) h1 = 255;
        int hl = h0 - base, hl2 = h1 - base;   // 0..15, <=16
        float pw = j*D; int w0 = (int)pw; if(w0 > 255) w0 = 255;
        float fw = pw - (float)w0;
        int w1 = w0+1; if(w1 > 255) w1 = 255;
        const float* r0 = rows + hl*256; const float* r1 = rows + hl2*256;
        float v = (1.f-fh)*((1.f-fw)*r0[w0] + fw*r0[w1])
                +      fh *((1.f-fw)*r1[w0] + fw*r1[w1]);
        xl[(size_t)bc*NPIX + i*64 + j] = v;
        ssq += v*v;
      }
    }
  }
  float wa = wave_sum(sum), wb = wave_sum(ssq);
  int w = threadIdx.x >> 6;
  if((threadIdx.x & 63) == 0){ sd[w] = wa; sd[8+w] = wb; }
  __syncthreads();
  if(threadIdx.x == 0){
    float a = 0.f, b2 = 0.f;
    #pragma unroll
    for(int k=0;k<8;k++){ a += sd[k]; b2 += sd[8+k]; }
    sum_low[bc] = a;
    ssql[bc]    = b2;
  }
}

// ---------------- Kernel 2: per-(b,d) sumsq of x_high ----------------
__global__ __launch_bounds__(256) void k_ssqh(const float* __restrict__ xh, float* __restrict__ ssqh){
  __shared__ float sd[4];
  int bd = blockIdx.x;
  const float4* P = (const float4*)(xh + (size_t)bd*NPIX);
  float s = 0.f;
  for(int i=threadIdx.x; i<NPIX/4; i+=256){
    float4 v = P[i];
    s += v.x*v.x + v.y*v.y + v.z*v.z + v.w*v.w;
  }
  float w = wave_sum(s);
  if((threadIdx.x & 63) == 0) sd[threadIdx.x >> 6] = w;
  __syncthreads();
  if(threadIdx.x == 0) ssqh[bd] = sd[0]+sd[1]+sd[2]+sd[3];
}

// ---------------- Kernel 3: cos partial dots over n-chunks of 64 ----------------
__global__ __launch_bounds__(256) void k_cospart(const float* __restrict__ xl,
                                                 const float* __restrict__ xh,
                                                 float* __restrict__ cospart){
  __shared__ float xls[64*65];
  __shared__ float xhs[128*65];
  int b = blockIdx.x >> 6;
  int chk = blockIdx.x & 63;
  int n0 = chk * 64;
  for(int idx = threadIdx.x; idx < 64*64; idx += 256){
    int c = idx >> 6, k = idx & 63;
    xls[c*65 + k] = xl[((size_t)b*64 + c)*NPIX + n0 + k];
  }
  for(int idx = threadIdx.x; idx < 128*64; idx += 256){
    int d = idx >> 6, k = idx & 63;
    xhs[d*65 + k] = xh[((size_t)b*128 + d)*NPIX + n0 + k];
  }
  __syncthreads();
  int ci = threadIdx.x & 15, di = threadIdx.x >> 4;
  int c0 = ci*4, d0 = di*8;
  float acc[4][8];
  #pragma unroll
  for(int i=0;i<4;i++)
    #pragma unroll
    for(int j=0;j<8;j++) acc[i][j] = 0.f;
  for(int k=0;k<64;k++){
    float a0 = xls[(c0+0)*65 + k];
    float a1 = xls[(c0+1)*65 + k];
    float a2 = xls[(c0+2)*65 + k];
    float a3 = xls[(c0+3)*65 + k];
    #pragma unroll
    for(int j=0;j<8;j++){
      float bv = xhs[(d0+j)*65 + k];
      acc[0][j] += a0*bv; acc[1][j] += a1*bv; acc[2][j] += a2*bv; acc[3][j] += a3*bv;
    }
  }
  float* op = cospart + (size_t)(b*64 + chk)*8192;
  #pragma unroll
  for(int i=0;i<4;i++){
    float4 v0 = make_float4(acc[i][0],acc[i][1],acc[i][2],acc[i][3]);
    float4 v1 = make_float4(acc[i][4],acc[i][5],acc[i][6],acc[i][7]);
    float4* dst = (float4*)(op + (c0+i)*128 + d0);
    dst[0] = v0; dst[1] = v1;
  }
}

// ---------------- Kernel 4: reduce partials, normalize, softmax over d -> p[b][c][d] ----------------
__global__ __launch_bounds__(128) void k_softmax(const float* __restrict__ cospart,
    const float* __restrict__ ssql, const float* __restrict__ ssqh, float* __restrict__ p){
  int b = blockIdx.x >> 6, c = blockIdx.x & 63;
  int d = threadIdx.x;
  float s = 0.f;
  for(int chk=0; chk<64; chk++)
    s += cospart[(size_t)(b*64 + chk)*8192 + c*128 + d];
  float nl = sqrtf(ssql[b*64 + c]) + 1e-12f;
  float nh = sqrtf(ssqh[b*128 + d]) + 1e-12f;
  float cosv = s / (nl * nh);
  __shared__ float sm[2], ssum[2];
  float m = cosv;
  #pragma unroll
  for(int o=32;o;o>>=1) m = fmaxf(m, __shfl_xor(m, o, 64));
  if((threadIdx.x & 63) == 0) sm[threadIdx.x >> 6] = m;
  __syncthreads();
  m = fmaxf(sm[0], sm[1]);
  float e = __expf(cosv - m);
  float t = e;
  #pragma unroll
  for(int o=32;o;o>>=1) t += __shfl_xor(t, o, 64);
  if((threadIdx.x & 63) == 0) ssum[threadIdx.x >> 6] = t;
  __syncthreads();
  t = ssum[0] + ssum[1];
  p[(size_t)(b*64 + c)*128 + d] = e * __builtin_amdgcn_rcpf(t);
}

// ---------------- Kernel 5: fused xhc = P @ xh and red64 = relu(bn(red_w @ xh)) ----------------
__global__ __launch_bounds__(256) void k_pv(const float* __restrict__ p, const float* __restrict__ red_w,
    const float* __restrict__ xh,
    const float* __restrict__ rg, const float* __restrict__ rb,
    const float* __restrict__ rm, const float* __restrict__ rv,
    float* __restrict__ xhc, float* __restrict__ red64){
  __shared__ float P_s[128*65];   // 33 KB
  int b = blockIdx.x >> 6, chk = blockIdx.x & 63;
  int n0 = chk * 64;
  int ni = threadIdx.x & 7, ri = threadIdx.x >> 3;
  int r0 = 4*ri;
  float acc[4][8];
  #pragma unroll
  for(int i=0;i<4;i++)
    #pragma unroll
    for(int j=0;j<8;j++) acc[i][j] = 0.f;
  const float* xrow = xh + (size_t)b*128*NPIX + n0 + 8*ni;
  for(int half=0; half<2; ++half){
    int kb = half*64;
    __syncthreads();
    for(int idx = threadIdx.x; idx < 128*64; idx += 256){
      int r = idx >> 6, kk = idx & 63;
      int k = kb + kk;
      P_s[r*65 + kk] = (r < 64) ? p[((size_t)b*64 + r)*128 + k]
                                : red_w[(size_t)(r-64)*128 + k];
    }
    __syncthreads();
    #pragma unroll 4
    for(int kk=0; kk<64; ++kk){
      int k = kb + kk;
      float4 x0 = *(const float4*)(xrow + (size_t)k*NPIX);
      float4 x1 = *(const float4*)(xrow + (size_t)k*NPIX + 4);
      #pragma unroll
      for(int rr=0; rr<4; rr++){
        float pw = P_s[(r0+rr)*65 + kk];
        acc[rr][0] += pw*x0.x; acc[rr][1] += pw*x0.y; acc[rr][2] += pw*x0.z; acc[rr][3] += pw*x0.w;
        acc[rr][4] += pw*x1.x; acc[rr][5] += pw*x1.y; acc[rr][6] += pw*x1.z; acc[rr][7] += pw*x1.w;
      }
    }
  }
  #pragma unroll
  for(int rr=0; rr<4; rr++){
    int r = r0 + rr;
    if(r < 64){
      float* dst = xhc + ((size_t)b*64 + r)*NPIX + n0 + 8*ni;
      *(float4*)dst     = make_float4(acc[rr][0],acc[rr][1],acc[rr][2],acc[rr][3]);
      *(float4*)(dst+4) = make_float4(acc[rr][4],acc[rr][5],acc[rr][6],acc[rr][7]);
    } else {
      int o = r - 64;
      float sc = rg[o] * rsqrtf(rv[o] + 1e-5f);
      float bs = rb[o] - rm[o]*sc;
      float* dst = red64 + ((size_t)b*64 + o)*NPIX + n0 + 8*ni;
      *(float4*)dst     = make_float4(fmaxf(fmaf(acc[rr][0],sc,bs),0.f), fmaxf(fmaf(acc[rr][1],sc,bs),0.f),
                                      fmaxf(fmaf(acc[rr][2],sc,bs),0.f), fmaxf(fmaf(acc[rr][3],sc,bs),0.f));
      *(float4*)(dst+4) = make_float4(fmaxf(fmaf(acc[rr][4],sc,bs),0.f), fmaxf(fmaf(acc[rr][5],sc,bs),0.f),
                                      fmaxf(fmaf(acc[rr][6],sc,bs),0.f), fmaxf(fmaf(acc[rr][7],sc,bs),0.f));
    }
  }
}

// ---------------- Kernel 6: weighted mean of upsampled red via Wv ----------------
__global__ __launch_bounds__(256) void k_redmean(const float* __restrict__ red64, float* __restrict__ redmean){
  __shared__ float wv[64];
  __shared__ float sd[4];
  int bo = blockIdx.x;
  if(threadIdx.x < 64){
    int i = threadIdx.x;
    const float U = 63.0f/255.0f;
    float acc = 0.f;
    for(int k=0;k<256;k++){
      float pos = k*U;
      int i0 = (int)pos; if(i0>63) i0=63;
      float f = pos - (float)i0;
      int i1 = i0+1; if(i1>63) i1=63;
      if(i0==i) acc += 1.0f - f;
      if(i1==i) acc += f;
    }
    wv[i] = acc;
  }
  __syncthreads();
  const float* R = red64 + (size_t)bo*NPIX;
  float acc = 0.f;
  for(int t=threadIdx.x; t<NPIX; t+=256){
    int i = t>>6, j = t&63;
    acc += wv[i]*wv[j]*R[t];
  }
  float w = wave_sum(acc);
  if((threadIdx.x & 63) == 0) sd[threadIdx.x >> 6] = w;
  __syncthreads();
  if(threadIdx.x == 0) redmean[bo] = (sd[0]+sd[1]+sd[2]+sd[3]) * (1.0f/65536.0f);
}

// ---------------- Kernel 7: final fused: att gate + 2x upsample + sigmoid diffs + relu ----------------
// grid = B*64*4: one block per (b, c, 64-row output slice). NO runtime-indexed private arrays:
// dw/dr selections are boolean cndmasks over statically-indexed registers (rule #20 fix).
__global__ __launch_bounds__(256) void k_final(const float* __restrict__ xlow,
    const float* __restrict__ xhc, const float* __restrict__ red64,
    const float* __restrict__ sum_low, const float* __restrict__ redmean,
    const float* __restrict__ cw, const float* __restrict__ cb,
    const float* __restrict__ g, const float* __restrict__ be,
    const float* __restrict__ mu, const float* __restrict__ va,
    float* __restrict__ out){
  __shared__ float sx[NRSTAGE*64];
  __shared__ float sr[NRSTAGE*64];
  __shared__ float s_red[2];
  __shared__ float s_att;
  int bc = blockIdx.x >> 2;        // b*64 + c
  int sl_ = blockIdx.x & 3;        // row-quarter
  int b = bc >> 6, c = bc & 63;
  int h_start = sl_ * 64;
  const float U = 63.0f/255.0f;
  int r_lo = (int)(h_start*U);
  // stage the input-row band of both 64x64 maps, float4-coalesced
  {
    const float* Ax = xhc   + (size_t)bc*NPIX;
    const float* Ar = red64 + (size_t)bc*NPIX;
    for(int i=threadIdx.x; i<NRSTAGE*16; i+=256){
      int row = i>>4, c4 = i&15;
      int srow = r_lo + row; if(srow > 63) srow = 63;
      ((float4*)sx)[i] = *(const float4*)(Ax + srow*64 + c4*4);
      ((float4*)sr)[i] = *(const float4*)(Ar + srow*64 + c4*4);
    }
  }
  // channel-gate att for this (b,c)
  if(threadIdx.x < 128){
    int j = threadIdx.x;
    float pj = (j < 64) ? sum_low[b*64 + j]*(1.0f/65536.0f) : redmean[b*64 + (j-64)];
    float t = cw[c*128 + j] * pj;
    float w = wave_sum(t);
    if((j & 63) == 0) s_red[j >> 6] = w;
  }
  __syncthreads();
  if(threadIdx.x == 0){
    float acc = s_red[0] + s_red[1] + cb[c];
    float sc = g[c] * rsqrtf(va[c] + 1e-5f);
    s_att = sigmoidf_((acc - mu[c])*sc + be[c]);
  }
  __syncthreads();
  float a = s_att;

  int ct = threadIdx.x & 63;   // column tile: output cols 4ct..4ct+3
  int rt = threadIdx.x >> 6;   // row group 0..3
  // column geometry: constant per thread; dw in {0,1} since 4-px span < 1 input cell
  float fw_[4]; bool dw_[4];
  int c0;
  {
    float pw0 = (4*ct)*U; c0 = (int)pw0; if(c0 > 63) c0 = 63;
    #pragma unroll
    for(int i=0;i<4;i++){
      int w = 4*ct + i;
      float pw = w*U;
      int w0 = (int)pw; if(w0 > 63) w0 = 63;
      fw_[i] = pw - (float)w0;
      dw_[i] = (w0 > c0);
    }
  }
  const float* XL = xlow + (size_t)bc*NLOW;
  float* O1 = out + ((size_t)(b*128) + c)*NLOW;
  float* O2 = O1 + (size_t)64*NLOW;

  #pragma unroll
  for(int it=0; it<4; ++it){
    int hbase = h_start + (it*4 + rt)*4;     // output rows hbase..hbase+3
    int r0 = (int)(hbase*U);
    // 3x3 clamped neighborhood from LDS (all indices static)
    float ax[3][3], ar[3][3];
    #pragma unroll
    for(int rr=0; rr<3; rr++){
      int rcl = r0 + rr; if(rcl > 63) rcl = 63;
      int rb_ = (rcl - r_lo)*64;
      #pragma unroll
      for(int cc=0; cc<3; cc++){
        int ccl = c0 + cc; if(ccl > 63) ccl = 63;
        ax[rr][cc] = sx[rb_ + ccl];
        ar[rr][cc] = sr[rb_ + ccl];
      }
    }
    // horizontal interp: select via cndmask, static indices only
    float tx[3][4], tr_[3][4];
    #pragma unroll
    for(int rr=0; rr<3; rr++){
      #pragma unroll
      for(int i=0;i<4;i++){
        float lx0 = dw_[i] ? ax[rr][1] : ax[rr][0];
        float lx1 = dw_[i] ? ax[rr][2] : ax[rr][1];
        tx[rr][i] = lx0 + fw_[i]*(lx1 - lx0);
        float lr0 = dw_[i] ? ar[rr][1] : ar[rr][0];
        float lr1 = dw_[i] ? ar[rr][2] : ar[rr][1];
        tr_[rr][i] = lr0 + fw_[i]*(lr1 - lr0);
      }
    }
    // vertical interp + sigmoid diffs
    #pragma unroll
    for(int hh=0; hh<4; ++hh){
      int h = hbase + hh;
      float ph = h*U;
      int h0 = (int)ph; if(h0 > 63) h0 = 63;
      float fh = ph - (float)h0;
      bool e = (h0 > r0);
      float4 xv = *(const float4*)(XL + h*256 + ct*4);
      float xvv[4] = {xv.x, xv.y, xv.z, xv.w};
      float o1[4], o2[4];
      #pragma unroll
      for(int i=0;i<4;i++){
        float ax0 = e ? tx[1][i] : tx[0][i];
        float ax1 = e ? tx[2][i] : tx[1][i];
        float vx = ax0 + fh*(ax1 - ax0);
        float ar0 = e ? tr_[1][i] : tr_[0][i];
        float ar1 = e ? tr_[2][i] : tr_[1][i];
        float vr = ar0 + fh*(ar1 - ar0);
        float sl = sigmoidf_(xvv[i]);
        o1[i] = fmaxf(sl - sigmoidf_(vx), 0.f);
        o2[i] = fmaxf(sl - sigmoidf_(vr*a), 0.f);
      }
      *(float4*)(O1 + h*256 + ct*4) = make_float4(o1[0],o1[1],o1[2],o1[3]);
      *(float4*)(O2 + h*256 + ct*4) = make_float4(o2[0],o2[1],o2[2],o2[3]);
    }
  }
}

extern "C" void kernel_launch(void* const* d_in, const int* in_sizes, int n_in,
                              void* d_out, int out_size, void* d_ws, size_t ws_size,
                              hipStream_t stream) {
  const float* x_low   = (const float*)d_in[0];
  const float* x_high  = (const float*)d_in[1];
  const float* red_w   = (const float*)d_in[2];
  const float* red_g   = (const float*)d_in[3];
  const float* red_b   = (const float*)d_in[4];
  const float* red_m   = (const float*)d_in[5];
  const float* red_v   = (const float*)d_in[6];
  const float* cconv_w = (const float*)d_in[7];
  const float* cconv_b = (const float*)d_in[8];
  const float* cc_g    = (const float*)d_in[9];
  const float* cc_b    = (const float*)d_in[10];
  const float* cc_m    = (const float*)d_in[11];
  const float* cc_v    = (const float*)d_in[12];
  float* out = (float*)d_out;
  float* ws  = (float*)d_ws;

  float* bufA    = ws;               // xl (2,097,152 floats), later red64
  float* bufB    = ws + 2097152;     // cospart (4,194,304), later xhc (2,097,152)
  float* p       = ws + 6291456;     // 65,536
  float* sum_low = ws + 6356992;     // 512
  float* ssql    = ws + 6357504;     // 512
  float* ssqh    = ws + 6358016;     // 1024
  float* redmean = ws + 6359040;     // 512

  hipLaunchKernelGGL(k_down,    dim3(512),  dim3(512), 0, stream, x_low, bufA, ssql, sum_low);
  hipLaunchKernelGGL(k_ssqh,    dim3(1024), dim3(256), 0, stream, x_high, ssqh);
  hipLaunchKernelGGL(k_cospart, dim3(512),  dim3(256), 0, stream, bufA, x_high, bufB);
  hipLaunchKernelGGL(k_softmax, dim3(512),  dim3(128), 0, stream, bufB, ssql, ssqh, p);
  hipLaunchKernelGGL(k_pv,      dim3(512),  dim3(256), 0, stream, p, red_w, x_high,
                     red_g, red_b, red_m, red_v, bufB, bufA);
  hipLaunchKernelGGL(k_redmean, dim3(512),  dim3(256), 0, stream, bufA, redmean);
  hipLaunchKernelGGL(k_final,   dim3(2048), dim3(256), 0, stream, x_low, bufB, bufA,
                     sum_low, redmean, cconv_w, cconv_b, cc_g, cc_b, cc_m, cc_v, out);
}

// Round 6
// 172.470 us; speedup vs baseline: 1.5251x; 1.0848x over previous
//
#include <hip/hip_runtime.h>
#include <math.h>

#define NPIX 4096     // 64*64
#define NLOW 65536    // 256*256
#define NRSTAGE 19    // max input rows needed by a 64-output-row slice

__device__ __forceinline__ float sigmoidf_(float x){
  return __builtin_amdgcn_rcpf(1.0f + __expf(-x));
}

__device__ __forceinline__ float wave_sum(float v){
  #pragma unroll
  for(int o=32;o;o>>=1) v += __shfl_down(v, o, 64);
  return v;
}

// ---------------- Kernel 1: heterogeneous pre-pass ----------------
// blocks [0,1024): half-channel downsample+sum of x_low (bc = bid>>1, half = bid&1)
// blocks [1024,1536): per-(b,d) sumsq of x_high, 2 channels per block
__global__ __launch_bounds__(512) void k_pre(const float* __restrict__ xlow,
    const float* __restrict__ xh,
    float* __restrict__ xl, float* __restrict__ ssql2, float* __restrict__ sum_low2,
    float* __restrict__ ssqh){
  __shared__ float rows[17*256];   // 17 KB
  __shared__ float sd[16];
  int bid = blockIdx.x;
  if(bid >= 1024){
    int s = bid - 1024;
    int h = threadIdx.x >> 8, tid = threadIdx.x & 255;
    int bd = 2*s + h;
    const float4* P = (const float4*)(xh + (size_t)bd*NPIX);
    float acc = 0.f;
    #pragma unroll
    for(int i=tid; i<1024; i+=256){
      float4 v = P[i];
      acc += v.x*v.x + v.y*v.y + v.z*v.z + v.w*v.w;
    }
    float w = wave_sum(acc);
    if((threadIdx.x & 63) == 0) sd[threadIdx.x >> 6] = w;
    __syncthreads();
    if(tid == 0) ssqh[bd] = sd[h*4+0]+sd[h*4+1]+sd[h*4+2]+sd[h*4+3];
    return;
  }
  int bc = bid >> 1, half = bid & 1;
  const float4* X4 = (const float4*)(xlow + (size_t)bc*NLOW);
  float4* R4 = (float4*)rows;
  const float D = 255.0f/63.0f;
  float sum = 0.f, ssq = 0.f;
  int rt = threadIdx.x >> 6, j = threadIdx.x & 63;

  for(int w=0; w<8; ++w){
    int it = half*8 + w;
    int base = 16*it;
    __syncthreads();   // protect previous window's reads
    for(int i=threadIdx.x; i<1024; i+=512){
      float4 v = X4[base*64 + i];
      R4[i] = v;
      sum += (v.x+v.y)+(v.z+v.w);
    }
    if(threadIdx.x < 64){
      int srow = base+16; if(srow > 255) srow = 255;
      R4[1024 + threadIdx.x] = X4[srow*64 + threadIdx.x];
    }
    __syncthreads();
    int i0 = (int)ceilf((float)base / D);
    int i = i0 + rt;
    if(i < 64){
      float ph = i*D; int h0 = (int)ph; if(h0 > 255) h0 = 255;
      if((h0 >> 4) == it){
        float fh = ph - (float)h0;
        int h1 = h0+1; if(h1 > 255) h1 = 255;
        int hl = h0 - base, hl2 = h1 - base;
        float pw = j*D; int w0 = (int)pw; if(w0 > 255) w0 = 255;
        float fw = pw - (float)w0;
        int w1 = w0+1; if(w1 > 255) w1 = 255;
        const float* r0 = rows + hl*256; const float* r1 = rows + hl2*256;
        float v = (1.f-fh)*((1.f-fw)*r0[w0] + fw*r0[w1])
                +      fh *((1.f-fw)*r1[w0] + fw*r1[w1]);
        xl[(size_t)bc*NPIX + i*64 + j] = v;
        ssq += v*v;
      }
    }
  }
  float wa = wave_sum(sum), wb = wave_sum(ssq);
  int wi = threadIdx.x >> 6;
  if((threadIdx.x & 63) == 0){ sd[wi] = wa; sd[8+wi] = wb; }
  __syncthreads();
  if(threadIdx.x == 0){
    float a = 0.f, b2 = 0.f;
    #pragma unroll
    for(int k=0;k<8;k++){ a += sd[k]; b2 += sd[8+k]; }
    sum_low2[bc*2 + half] = a;
    ssql2[bc*2 + half]    = b2;
  }
}

// ---------------- Kernel 2: cos partial dots over n-chunks of 64 ----------------
__global__ __launch_bounds__(256) void k_cospart(const float* __restrict__ xl,
                                                 const float* __restrict__ xh,
                                                 float* __restrict__ cospart){
  __shared__ float xls[64*65];
  __shared__ float xhs[128*65];
  int b = blockIdx.x >> 6;
  int chk = blockIdx.x & 63;
  int n0 = chk * 64;
  for(int idx = threadIdx.x; idx < 64*64; idx += 256){
    int c = idx >> 6, k = idx & 63;
    xls[c*65 + k] = xl[((size_t)b*64 + c)*NPIX + n0 + k];
  }
  for(int idx = threadIdx.x; idx < 128*64; idx += 256){
    int d = idx >> 6, k = idx & 63;
    xhs[d*65 + k] = xh[((size_t)b*128 + d)*NPIX + n0 + k];
  }
  __syncthreads();
  int ci = threadIdx.x & 15, di = threadIdx.x >> 4;
  int c0 = ci*4, d0 = di*8;
  float acc[4][8];
  #pragma unroll
  for(int i=0;i<4;i++)
    #pragma unroll
    for(int j=0;j<8;j++) acc[i][j] = 0.f;
  for(int k=0;k<64;k++){
    float a0 = xls[(c0+0)*65 + k];
    float a1 = xls[(c0+1)*65 + k];
    float a2 = xls[(c0+2)*65 + k];
    float a3 = xls[(c0+3)*65 + k];
    #pragma unroll
    for(int j=0;j<8;j++){
      float bv = xhs[(d0+j)*65 + k];
      acc[0][j] += a0*bv; acc[1][j] += a1*bv; acc[2][j] += a2*bv; acc[3][j] += a3*bv;
    }
  }
  float* op = cospart + (size_t)(b*64 + chk)*8192;
  #pragma unroll
  for(int i=0;i<4;i++){
    float4 v0 = make_float4(acc[i][0],acc[i][1],acc[i][2],acc[i][3]);
    float4 v1 = make_float4(acc[i][4],acc[i][5],acc[i][6],acc[i][7]);
    float4* dst = (float4*)(op + (c0+i)*128 + d0);
    dst[0] = v0; dst[1] = v1;
  }
}

// ---------------- Kernel 3: reduce partials, normalize, softmax over d -> p[b][c][d] ----------------
__global__ __launch_bounds__(128) void k_softmax(const float* __restrict__ cospart,
    const float* __restrict__ ssql2, const float* __restrict__ ssqh, float* __restrict__ p){
  int b = blockIdx.x >> 6, c = blockIdx.x & 63;
  int d = threadIdx.x;
  float s = 0.f;
  for(int chk=0; chk<64; chk++)
    s += cospart[(size_t)(b*64 + chk)*8192 + c*128 + d];
  float nl = sqrtf(ssql2[(b*64 + c)*2] + ssql2[(b*64 + c)*2 + 1]) + 1e-12f;
  float nh = sqrtf(ssqh[b*128 + d]) + 1e-12f;
  float cosv = s / (nl * nh);
  __shared__ float sm[2], ssum[2];
  float m = cosv;
  #pragma unroll
  for(int o=32;o;o>>=1) m = fmaxf(m, __shfl_xor(m, o, 64));
  if((threadIdx.x & 63) == 0) sm[threadIdx.x >> 6] = m;
  __syncthreads();
  m = fmaxf(sm[0], sm[1]);
  float e = __expf(cosv - m);
  float t = e;
  #pragma unroll
  for(int o=32;o;o>>=1) t += __shfl_xor(t, o, 64);
  if((threadIdx.x & 63) == 0) ssum[threadIdx.x >> 6] = t;
  __syncthreads();
  t = ssum[0] + ssum[1];
  p[(size_t)(b*64 + c)*128 + d] = e * __builtin_amdgcn_rcpf(t);
}

// ---------------- Kernel 4: fused xhc = P @ xh, red64 = relu(bn(red_w @ xh)), redmean partials ----
// grid = B * 64 n-chunks of 64. n-chunk == row `chk` of the 64x64 map, so the pooled-mean
// partial for this block is wv[chk] * sum_j wv[j]*red[o][j] -> part_buf[b][o][chk] (no atomics).
__global__ __launch_bounds__(256) void k_pv(const float* __restrict__ p, const float* __restrict__ red_w,
    const float* __restrict__ xh,
    const float* __restrict__ rg, const float* __restrict__ rb,
    const float* __restrict__ rm, const float* __restrict__ rv,
    float* __restrict__ xhc, float* __restrict__ red64, float* __restrict__ part_buf){
  __shared__ float P_s[128*65];   // 33 KB
  __shared__ float wvv[64];
  int b = blockIdx.x >> 6, chk = blockIdx.x & 63;
  int n0 = chk * 64;
  int ni = threadIdx.x & 7, ri = threadIdx.x >> 3;
  int r0 = 4*ri;
  // upsample-weight table (covered by the first __syncthreads below)
  if(threadIdx.x < 64){
    int i = threadIdx.x;
    const float U = 63.0f/255.0f;
    float acc = 0.f;
    for(int k=0;k<256;k++){
      float pos = k*U;
      int i0 = (int)pos; if(i0>63) i0=63;
      float f = pos - (float)i0;
      int i1 = i0+1; if(i1>63) i1=63;
      if(i0==i) acc += 1.0f - f;
      if(i1==i) acc += f;
    }
    wvv[i] = acc;
  }
  float acc[4][8];
  #pragma unroll
  for(int i=0;i<4;i++)
    #pragma unroll
    for(int j=0;j<8;j++) acc[i][j] = 0.f;
  const float* xrow = xh + (size_t)b*128*NPIX + n0 + 8*ni;
  for(int half=0; half<2; ++half){
    int kb = half*64;
    __syncthreads();
    for(int idx = threadIdx.x; idx < 128*64; idx += 256){
      int r = idx >> 6, kk = idx & 63;
      int k = kb + kk;
      P_s[r*65 + kk] = (r < 64) ? p[((size_t)b*64 + r)*128 + k]
                                : red_w[(size_t)(r-64)*128 + k];
    }
    __syncthreads();
    #pragma unroll 4
    for(int kk=0; kk<64; ++kk){
      int k = kb + kk;
      float4 x0 = *(const float4*)(xrow + (size_t)k*NPIX);
      float4 x1 = *(const float4*)(xrow + (size_t)k*NPIX + 4);
      #pragma unroll
      for(int rr=0; rr<4; rr++){
        float pw = P_s[(r0+rr)*65 + kk];
        acc[rr][0] += pw*x0.x; acc[rr][1] += pw*x0.y; acc[rr][2] += pw*x0.z; acc[rr][3] += pw*x0.w;
        acc[rr][4] += pw*x1.x; acc[rr][5] += pw*x1.y; acc[rr][6] += pw*x1.z; acc[rr][7] += pw*x1.w;
      }
    }
  }
  if(r0 < 64){
    #pragma unroll
    for(int rr=0; rr<4; rr++){
      int r = r0 + rr;
      float* dst = xhc + ((size_t)b*64 + r)*NPIX + n0 + 8*ni;
      *(float4*)dst     = make_float4(acc[rr][0],acc[rr][1],acc[rr][2],acc[rr][3]);
      *(float4*)(dst+4) = make_float4(acc[rr][4],acc[rr][5],acc[rr][6],acc[rr][7]);
    }
  } else {
    float wj[8];
    #pragma unroll
    for(int jj=0;jj<8;jj++) wj[jj] = wvv[8*ni + jj];
    float wchk = wvv[chk];
    #pragma unroll
    for(int rr=0; rr<4; rr++){
      int o = r0 + rr - 64;
      float sc = rg[o] * rsqrtf(rv[o] + 1e-5f);
      float bs = rb[o] - rm[o]*sc;
      float v[8];
      #pragma unroll
      for(int jj=0;jj<8;jj++) v[jj] = fmaxf(fmaf(acc[rr][jj],sc,bs),0.f);
      float* dst = red64 + ((size_t)b*64 + o)*NPIX + n0 + 8*ni;
      *(float4*)dst     = make_float4(v[0],v[1],v[2],v[3]);
      *(float4*)(dst+4) = make_float4(v[4],v[5],v[6],v[7]);
      float part = 0.f;
      #pragma unroll
      for(int jj=0;jj<8;jj++) part += wj[jj]*v[jj];
      #pragma unroll
      for(int off=1; off<8; off<<=1) part += __shfl_xor(part, off, 64);
      if(ni == 0) part_buf[((size_t)b*64 + o)*64 + chk] = wchk * part;
    }
  }
}

// ---------------- Kernel 5: final fused: att gate + 2x upsample + sigmoid diffs + relu ----------------
// grid = B*64*4: one block per (b, c, 64-row output slice). All private indexing static (rule #20).
__global__ __launch_bounds__(256) void k_final(const float* __restrict__ xlow,
    const float* __restrict__ xhc, const float* __restrict__ red64,
    const float* __restrict__ sum_low2, const float* __restrict__ part_buf,
    const float* __restrict__ cw, const float* __restrict__ cb,
    const float* __restrict__ g, const float* __restrict__ be,
    const float* __restrict__ mu, const float* __restrict__ va,
    float* __restrict__ out){
  __shared__ float sx[NRSTAGE*64];
  __shared__ float sr[NRSTAGE*64];
  __shared__ float s_red[2];
  __shared__ float s_att;
  int bc = blockIdx.x >> 2;        // b*64 + c
  int sl_ = blockIdx.x & 3;        // row-quarter
  int b = bc >> 6, c = bc & 63;
  int h_start = sl_ * 64;
  const float U = 63.0f/255.0f;
  int r_lo = (int)(h_start*U);
  // stage the input-row band of both 64x64 maps, float4-coalesced
  {
    const float* Ax = xhc   + (size_t)bc*NPIX;
    const float* Ar = red64 + (size_t)bc*NPIX;
    for(int i=threadIdx.x; i<NRSTAGE*16; i+=256){
      int row = i>>4, c4 = i&15;
      int srow = r_lo + row; if(srow > 63) srow = 63;
      ((float4*)sx)[i] = *(const float4*)(Ax + srow*64 + c4*4);
      ((float4*)sr)[i] = *(const float4*)(Ar + srow*64 + c4*4);
    }
  }
  // channel-gate att for this (b,c)
  if(threadIdx.x < 128){
    int j = threadIdx.x;
    float pj;
    if(j < 64){
      pj = (sum_low2[(b*64 + j)*2] + sum_low2[(b*64 + j)*2 + 1]) * (1.0f/65536.0f);
    } else {
      const float4* pr = (const float4*)(part_buf + ((size_t)b*64 + (j-64))*64);
      float s4 = 0.f;
      #pragma unroll
      for(int q=0;q<16;q++){ float4 v = pr[q]; s4 += (v.x+v.y)+(v.z+v.w); }
      pj = s4 * (1.0f/65536.0f);
    }
    float t = cw[c*128 + j] * pj;
    float w = wave_sum(t);
    if((j & 63) == 0) s_red[j >> 6] = w;
  }
  __syncthreads();
  if(threadIdx.x == 0){
    float acc = s_red[0] + s_red[1] + cb[c];
    float sc = g[c] * rsqrtf(va[c] + 1e-5f);
    s_att = sigmoidf_((acc - mu[c])*sc + be[c]);
  }
  __syncthreads();
  float a = s_att;

  int ct = threadIdx.x & 63;   // column tile: output cols 4ct..4ct+3
  int rt = threadIdx.x >> 6;   // row group 0..3
  float fw_[4]; bool dw_[4];
  int c0;
  {
    float pw0 = (4*ct)*U; c0 = (int)pw0; if(c0 > 63) c0 = 63;
    #pragma unroll
    for(int i=0;i<4;i++){
      int w = 4*ct + i;
      float pw = w*U;
      int w0 = (int)pw; if(w0 > 63) w0 = 63;
      fw_[i] = pw - (float)w0;
      dw_[i] = (w0 > c0);
    }
  }
  const float* XL = xlow + (size_t)bc*NLOW;
  float* O1 = out + ((size_t)(b*128) + c)*NLOW;
  float* O2 = O1 + (size_t)64*NLOW;

  #pragma unroll
  for(int it=0; it<4; ++it){
    int hbase = h_start + (it*4 + rt)*4;
    int r0 = (int)(hbase*U);
    float ax[3][3], ar[3][3];
    #pragma unroll
    for(int rr=0; rr<3; rr++){
      int rcl = r0 + rr; if(rcl > 63) rcl = 63;
      int rb_ = (rcl - r_lo)*64;
      #pragma unroll
      for(int cc=0; cc<3; cc++){
        int ccl = c0 + cc; if(ccl > 63) ccl = 63;
        ax[rr][cc] = sx[rb_ + ccl];
        ar[rr][cc] = sr[rb_ + ccl];
      }
    }
    float tx[3][4], tr_[3][4];
    #pragma unroll
    for(int rr=0; rr<3; rr++){
      #pragma unroll
      for(int i=0;i<4;i++){
        float lx0 = dw_[i] ? ax[rr][1] : ax[rr][0];
        float lx1 = dw_[i] ? ax[rr][2] : ax[rr][1];
        tx[rr][i] = lx0 + fw_[i]*(lx1 - lx0);
        float lr0 = dw_[i] ? ar[rr][1] : ar[rr][0];
        float lr1 = dw_[i] ? ar[rr][2] : ar[rr][1];
        tr_[rr][i] = lr0 + fw_[i]*(lr1 - lr0);
      }
    }
    #pragma unroll
    for(int hh=0; hh<4; ++hh){
      int h = hbase + hh;
      float ph = h*U;
      int h0 = (int)ph; if(h0 > 63) h0 = 63;
      float fh = ph - (float)h0;
      bool e = (h0 > r0);
      float4 xv = *(const float4*)(XL + h*256 + ct*4);
      float xvv[4] = {xv.x, xv.y, xv.z, xv.w};
      float o1[4], o2[4];
      #pragma unroll
      for(int i=0;i<4;i++){
        float ax0 = e ? tx[1][i] : tx[0][i];
        float ax1 = e ? tx[2][i] : tx[1][i];
        float vx = ax0 + fh*(ax1 - ax0);
        float ar0 = e ? tr_[1][i] : tr_[0][i];
        float ar1 = e ? tr_[2][i] : tr_[1][i];
        float vr = ar0 + fh*(ar1 - ar0);
        float sl = sigmoidf_(xvv[i]);
        o1[i] = fmaxf(sl - sigmoidf_(vx), 0.f);
        o2[i] = fmaxf(sl - sigmoidf_(vr*a), 0.f);
      }
      *(float4*)(O1 + h*256 + ct*4) = make_float4(o1[0],o1[1],o1[2],o1[3]);
      *(float4*)(O2 + h*256 + ct*4) = make_float4(o2[0],o2[1],o2[2],o2[3]);
    }
  }
}

extern "C" void kernel_launch(void* const* d_in, const int* in_sizes, int n_in,
                              void* d_out, int out_size, void* d_ws, size_t ws_size,
                              hipStream_t stream) {
  const float* x_low   = (const float*)d_in[0];
  const float* x_high  = (const float*)d_in[1];
  const float* red_w   = (const float*)d_in[2];
  const float* red_g   = (const float*)d_in[3];
  const float* red_b   = (const float*)d_in[4];
  const float* red_m   = (const float*)d_in[5];
  const float* red_v   = (const float*)d_in[6];
  const float* cconv_w = (const float*)d_in[7];
  const float* cconv_b = (const float*)d_in[8];
  const float* cc_g    = (const float*)d_in[9];
  const float* cc_b    = (const float*)d_in[10];
  const float* cc_m    = (const float*)d_in[11];
  const float* cc_v    = (const float*)d_in[12];
  float* out = (float*)d_out;
  float* ws  = (float*)d_ws;

  float* bufA     = ws;               // xl (2,097,152 floats), later red64
  float* bufB     = ws + 2097152;     // cospart (4,194,304), later xhc (2,097,152)
  float* p        = ws + 6291456;     // 65,536
  float* sum_low2 = ws + 6356992;     // 1024
  float* ssql2    = ws + 6358016;     // 1024
  float* ssqh     = ws + 6359040;     // 1024
  float* part_buf = ws + 6360064;     // 32,768

  hipLaunchKernelGGL(k_pre,     dim3(1536), dim3(512), 0, stream, x_low, x_high,
                     bufA, ssql2, sum_low2, ssqh);
  hipLaunchKernelGGL(k_cospart, dim3(512),  dim3(256), 0, stream, bufA, x_high, bufB);
  hipLaunchKernelGGL(k_softmax, dim3(512),  dim3(128), 0, stream, bufB, ssql2, ssqh, p);
  hipLaunchKernelGGL(k_pv,      dim3(512),  dim3(256), 0, stream, p, red_w, x_high,
                     red_g, red_b, red_m, red_v, bufB, bufA, part_buf);
  hipLaunchKernelGGL(k_final,   dim3(2048), dim3(256), 0, stream, x_low, bufB, bufA,
                     sum_low2, part_buf, cconv_w, cconv_b, cc_g, cc_b, cc_m, cc_v, out);
}